// Round 1
// baseline (200.744 us; speedup 1.0000x reference)
//
#include <hip/hip_runtime.h>
#include <math.h>
#include <float.h>

#define W 1024
#define IMG_SZ (1024*1024)
#define N_IMG 32
#define RPC 6                          // interior rows computed per chunk
#define RING 16                        // LDS ring: 16 rows * 4 KB = 64 KB
#define CPI 171                        // ceil(1022/6) chunks per image
#define BPI 16                         // blocks per image
#define NB (N_IMG*BPI)                 // 512 blocks = 2 blocks/CU, all resident

// curv = Dxy*(Dx-Dy)^2 / (2h*(Dx^2+Dy^2)^1.5 + 16 h^4 * 1e-8)
#define TWO_H    0.122f
#define C_EPS    2.2153332e-12f        // 16 * 0.061^4 * 1e-8

typedef const __attribute__((address_space(1))) void* gas_p;
typedef __attribute__((address_space(3))) void*       las_p;

__device__ __forceinline__ void gload_lds16(const float* gp, float* lp) {
    __builtin_amdgcn_global_load_lds((gas_p)gp, (las_p)lp, 16, 0, 0);
}

// counted vmcnt wait — memory clobber orders compiler-emitted ds/global ops
#define WAITV(N) asm volatile("s_waitcnt vmcnt(" #N ")" ::: "memory")

__device__ __forceinline__ void bar() {
    __builtin_amdgcn_sched_barrier(0);
    __builtin_amdgcn_s_barrier();
    __builtin_amdgcn_sched_barrier(0);
}

struct Px { float num, den, mn; };

__device__ __forceinline__ Px px(const float T[6], const float M[6], const float B[6], int j) {
    Px p;
    const float Dx  = M[j+2] - M[j];
    const float Dy  = B[j+1] - T[j+1];
    const float Dxy = (B[j+2] - B[j]) - T[j+2] + T[j];
    const float dif = Dx - Dy;
    p.num = Dxy * (dif * dif);
    const float s = Dx*Dx + Dy*Dy;
    p.den = TWO_H * (s * __builtin_amdgcn_sqrtf(s)) + C_EPS;
    const float c = M[j+1];
    p.mn = fminf(fminf(c*M[j], c*M[j+2]), fminf(c*T[j+1], c*B[j+1]));
    return p;
}

// shared reciprocal for two pixels: den>=C_EPS so den*den >= 4.9e-24 (no underflow)
__device__ __forceinline__ void pair(const Px& a, const Px& b, float ea, float eb,
                                     float& fsum, int& cnt) {
    const float rc = __builtin_amdgcn_rcpf(a.den * b.den);
    const float t0 = a.num * (b.den * rc);
    const float t1 = b.num * (a.den * rc);
    const float cr0 = fmaxf(t0*t0 - 1.0f, 0.0f);
    const float cr1 = fmaxf(t1*t1 - 1.0f, 0.0f);
    const bool k0 = fmaxf(a.mn, ea) < 0.0f;
    const bool k1 = fmaxf(b.mn, eb) < 0.0f;
    fsum += k0 ? cr0 : 0.0f;
    fsum += k1 ? cr1 : 0.0f;
    cnt += __popcll(__ballot(k0));     // scalar-pipe; cnt becomes wave-uniform
    cnt += __popcll(__ballot(k1));
}

__device__ __forceinline__ void do_row(const float T[6], const float M[6], const float B[6],
                                       float e0, float e3, float& fsum, int& cnt) {
    const Px p0 = px(T, M, B, 0);
    const Px p1 = px(T, M, B, 1);
    const Px p2 = px(T, M, B, 2);
    const Px p3 = px(T, M, B, 3);
    pair(p0, p1, e0,      -FLT_MAX, fsum, cnt);
    pair(p2, p3, -FLT_MAX, e3,      fsum, cnt);
}

__device__ __forceinline__ void read_win(const float* tile, int slot, int x4,
                                         int ixl, int ixr, float w[6]) {
    const float* row = tile + slot * W;
    const float4 v = *reinterpret_cast<const float4*>(row + x4);  // ds_read_b128
    w[1] = v.x; w[2] = v.y; w[3] = v.z; w[4] = v.w;
    w[0] = row[ixl];
    w[5] = row[ixr];
}

// stage logical rows g0..g0+NR-1 into ring slots (g & 15); whole block cooperates,
// each wave stages a contiguous 1 KB quarter-row (wave-uniform LDS base + lane*16)
template<int NR>
__device__ __forceinline__ void stage_rows(const float* __restrict__ img, float* tile,
                                           int g0, int q) {
#pragma unroll
    for (int i = 0; i < NR; ++i) {
        const int g = g0 + i;
        const int rowg = (g < 1023) ? g : 1023;        // clamp at image bottom
        gload_lds16(img + (size_t)rowg * W + q * 4, &tile[(g & (RING-1)) * W + q * 4]);
    }
}

__global__ __launch_bounds__(256, 2) void curv_partial(const float* __restrict__ phi,
                                                       double* __restrict__ partial, int nb) {
    __shared__ float tile[RING * W];        // 64 KB ring
    const int q = threadIdx.x;              // pixels x = 4q..4q+3
    const int lane = q & 63;
    const int wv = q >> 6;
    const int x4 = q * 4;
    const int ixl = (x4 > 0) ? x4 - 1 : 0;          // clamped halo indices (edge-masked later)
    const int ixr = (x4 + 4 < W) ? x4 + 4 : W - 1;
    const float edge0 = (q == 0)   ? 1.0f : -FLT_MAX;   // kills x=0
    const float edge3 = (q == 255) ? 1.0f : -FLT_MAX;   // kills x=1023

    double sum = 0.0, dcnt = 0.0;

    // each "run" = contiguous chunk range of one image; NB runs total
    for (int run = (int)blockIdx.x; run < NB; run += nb) {
        const int n = run >> 4;            // run / BPI
        const int j = run & (BPI - 1);
        const int qq = CPI / BPI;          // 10
        const int r  = CPI - qq * BPI;     // 11
        const int cst = j * qq + (j < r ? j : r);
        const int clen = qq + (j < r ? 1 : 0);
        const int cen = cst + clen;
        const float* img = phi + (size_t)n * IMG_SZ;

        // ---- prologue: stage window cst (8 rows) + new rows of window cst+1 ----
        stage_rows<8>(img, tile, 6 * cst, q);
        if (cst + 1 < cen) {
            stage_rows<6>(img, tile, 6 * cst + 8, q);
            WAITV(6);                       // drain window cst, keep cst+1 in flight
        } else {
            WAITV(0);
        }
        bar();

        for (int ci = cst; ci < cen; ++ci) {
            const int y0 = 1 + 6 * ci;
            const int nri = (RPC < 1023 - y0) ? RPC : (1023 - y0);
            const int b0 = 6 * ci;          // logical first row of window (y0-1)

            // ---- compute window ci from LDS ring (3-row register rotation) ----
            float fs = 0.0f;
            int ct = 0;
            float R0[6], R1[6], R2[6];
            read_win(tile, (b0)     & (RING-1), x4, ixl, ixr, R0);
            read_win(tile, (b0 + 1) & (RING-1), x4, ixl, ixr, R1);
#pragma unroll
            for (int rr = 0; rr < RPC; rr += 3) {
                if (rr < nri) {
                    read_win(tile, (b0 + rr + 2) & (RING-1), x4, ixl, ixr, R2);
                    do_row(R0, R1, R2, edge0, edge3, fs, ct);
                }
                if (rr + 1 < nri) {
                    read_win(tile, (b0 + rr + 3) & (RING-1), x4, ixl, ixr, R0);
                    do_row(R1, R2, R0, edge0, edge3, fs, ct);
                }
                if (rr + 2 < nri) {
                    read_win(tile, (b0 + rr + 4) & (RING-1), x4, ixl, ixr, R1);
                    do_row(R2, R0, R1, edge0, edge3, fs, ct);
                }
            }
            sum  += (double)fs;
            dcnt += (double)ct;             // wave-uniform

            if (ci + 1 >= cen) break;       // last chunk of run: nothing left in flight

            bar();                          // all waves done reading window ci slots
            if (ci + 2 < cen) {
                // new rows of window ci+2: 6ci+14..6ci+19 -> slots {14,15,0,1,2,3}+6ci,
                // disjoint from window ci+1's read slots {6..13}+6ci (mod 16)
                stage_rows<6>(img, tile, 6 * ci + 14, q);
                WAITV(6);                   // drain window ci+1 loads, keep ci+2 flying
            } else {
                WAITV(0);                   // tail: drain window ci+1
            }
            bar();                          // window ci+1 fully in LDS (all waves waited)
        }

        bar();                              // protect ring before next run (fallback path)
    }

    // fsum: shuffle-reduce; cnt already wave-uniform
    for (int off = 32; off > 0; off >>= 1)
        sum += __shfl_down(sum, off, 64);
    __shared__ double lsum[4], lcnt[4];
    if (lane == 0) { lsum[wv] = sum; lcnt[wv] = dcnt; }
    __syncthreads();
    if (q == 0) {
        partial[blockIdx.x]      = lsum[0] + lsum[1] + lsum[2] + lsum[3];
        partial[nb + blockIdx.x] = lcnt[0] + lcnt[1] + lcnt[2] + lcnt[3];
    }
}

__global__ __launch_bounds__(256) void curv_final(const double* __restrict__ partial,
                                                  int nb, float* __restrict__ out) {
    double s = 0.0, c = 0.0;
    for (int i = threadIdx.x; i < nb; i += 256) {
        s += partial[i];
        c += partial[nb + i];
    }
    for (int off = 32; off > 0; off >>= 1) {
        s += __shfl_down(s, off, 64);
        c += __shfl_down(c, off, 64);
    }
    __shared__ double lsum[4], lcnt[4];
    const int lane = threadIdx.x & 63, wv = threadIdx.x >> 6;
    if (lane == 0) { lsum[wv] = s; lcnt[wv] = c; }
    __syncthreads();
    if (threadIdx.x == 0) {
        const double S = lsum[0] + lsum[1] + lsum[2] + lsum[3];
        const double C = lcnt[0] + lcnt[1] + lcnt[2] + lcnt[3];
        out[0] = (float)(S / (C + 1e-8));
    }
}

extern "C" void kernel_launch(void* const* d_in, const int* in_sizes, int n_in,
                              void* d_out, int out_size, void* d_ws, size_t ws_size,
                              hipStream_t stream) {
    const float* phi = (const float*)d_in[0];
    float* out = (float*)d_out;
    double* partial = (double*)d_ws;

    int nb = NB;
    const size_t need = (size_t)nb * 2 * sizeof(double);
    if (ws_size < need) {
        nb = (int)(ws_size / (2 * sizeof(double)));
        if (nb < 1) nb = 1;
    }

    curv_partial<<<nb, 256, 0, stream>>>(phi, partial, nb);
    curv_final<<<1, 256, 0, stream>>>(partial, nb, out);
}

// Round 2
// 197.931 us; speedup vs baseline: 1.0142x; 1.0142x over previous
//
#include <hip/hip_runtime.h>
#include <math.h>
#include <float.h>

#define W 1024
#define IMG_SZ (1024*1024)
#define N_IMG 32
#define RPS 8                           // interior rows per strip
#define SPI 128                         // strips per image: 127*8 + 6 = 1022 interior rows
#define NSTRIP (N_IMG*SPI)              // 4096 strips, one per wave
#define NBLK 1024                       // 1024 blocks * 4 waves = 4096 waves

// curv = Dxy*(Dx-Dy)^2 / (2h*(Dx^2+Dy^2)^1.5 + 16 h^4 * 1e-8)
#define TWO_H    0.122f
#define C_EPS    2.2153332e-12f        // 16 * 0.061^4 * 1e-8

// One image row, per-lane view: 16 contiguous px (x = 16*lane .. 16*lane+15)
// plus left/right halo scalars. 18 VGPRs. No LDS anywhere.
struct RowV { float4 a, b, c, d; float l, r; };

__device__ __forceinline__ void issue_row(const float* __restrict__ rp, int dl, int dr, RowV& v) {
    v.a = *reinterpret_cast<const float4*>(rp);
    v.b = *reinterpret_cast<const float4*>(rp + 4);
    v.c = *reinterpret_cast<const float4*>(rp + 8);
    v.d = *reinterpret_cast<const float4*>(rp + 12);
    v.l = rp[dl];                       // x = 16*lane-1 (same cacheline as neighbor lane)
    v.r = rp[dr];                       // x = 16*lane+16
}

__device__ __forceinline__ void unpack(const RowV& v, float w[18]) {
    w[0]=v.l;
    w[1]=v.a.x;  w[2]=v.a.y;  w[3]=v.a.z;  w[4]=v.a.w;
    w[5]=v.b.x;  w[6]=v.b.y;  w[7]=v.b.z;  w[8]=v.b.w;
    w[9]=v.c.x;  w[10]=v.c.y; w[11]=v.c.z; w[12]=v.c.w;
    w[13]=v.d.x; w[14]=v.d.y; w[15]=v.d.z; w[16]=v.d.w;
    w[17]=v.r;
}

struct Px { float num, den, mn; };

__device__ __forceinline__ Px px(const float T[18], const float M[18], const float B[18], int j) {
    Px p;
    const float Dx  = M[j+2] - M[j];
    const float Dy  = B[j+1] - T[j+1];
    const float Dxy = (B[j+2] - B[j]) - T[j+2] + T[j];
    const float dif = Dx - Dy;
    p.num = Dxy * (dif * dif);
    const float s = Dx*Dx + Dy*Dy;
    p.den = TWO_H * (s * __builtin_amdgcn_sqrtf(s)) + C_EPS;
    const float c = M[j+1];
    p.mn = fminf(fminf(c*M[j], c*M[j+2]), fminf(c*T[j+1], c*B[j+1]));
    return p;
}

// shared reciprocal for two pixels: den>=C_EPS so den*den >= 4.9e-24 (no underflow)
__device__ __forceinline__ void pair(const Px& a, const Px& b, float ea, float eb,
                                     float& fsum, int& cnt) {
    const float rc = __builtin_amdgcn_rcpf(a.den * b.den);
    const float t0 = a.num * (b.den * rc);
    const float t1 = b.num * (a.den * rc);
    const float cr0 = fmaxf(t0*t0 - 1.0f, 0.0f);
    const float cr1 = fmaxf(t1*t1 - 1.0f, 0.0f);
    const bool k0 = fmaxf(a.mn, ea) < 0.0f;
    const bool k1 = fmaxf(b.mn, eb) < 0.0f;
    fsum += k0 ? cr0 : 0.0f;
    fsum += k1 ? cr1 : 0.0f;
    cnt += __popcll(__ballot(k0));     // scalar-pipe; cnt becomes wave-uniform
    cnt += __popcll(__ballot(k1));
}

__device__ __forceinline__ void do_row16(const float T[18], const float M[18], const float B[18],
                                         float e0, float e3, float& fsum, int& cnt) {
#pragma unroll
    for (int j = 0; j < 16; j += 2) {
        const Px p0 = px(T, M, B, j);
        const Px p1 = px(T, M, B, j + 1);
        pair(p0, p1, (j == 0) ? e0 : -FLT_MAX, (j == 14) ? e3 : -FLT_MAX, fsum, cnt);
    }
}

__global__ __launch_bounds__(256, 2) void curv_partial(const float* __restrict__ phi,
                                                       double* __restrict__ partial, int nb) {
    const int q = threadIdx.x;
    const int lane = q & 63;
    const int wv = q >> 6;
    // halo offsets relative to this lane's 16-px window start (clamped at image edges;
    // the clamped values feed only edge-killed pixels)
    const int dl = (lane == 0)  ? 0  : -1;
    const int dr = (lane == 63) ? 15 : 16;
    const float edge0 = (lane == 0)  ? 1.0f : -FLT_MAX;   // kills x=0
    const float edge3 = (lane == 63) ? 1.0f : -FLT_MAX;   // kills x=1023

    double sum = 0.0, dcnt = 0.0;
    const int nw = nb * 4;              // total waves

    // one strip (8 interior rows of one image) per wave; waves fully independent
    for (int sidx = (int)blockIdx.x * 4 + wv; sidx < NSTRIP; sidx += nw) {
        const int n = sidx >> 7;        // / SPI
        const int s = sidx & (SPI - 1);
        const int y0 = 1 + s * RPS;
        const int nr = (RPS < 1023 - y0) ? RPS : (1023 - y0);   // 8, last strip 6
        const float* base = phi + (size_t)n * IMG_SZ + lane * 16;

        RowV R[4];                      // register ring: row (y0-1+t) lives in R[t&3]
        issue_row(base + (size_t)(y0 - 1) * W, dl, dr, R[0]);
        issue_row(base + (size_t)(y0)     * W, dl, dr, R[1]);
        issue_row(base + (size_t)(y0 + 1) * W, dl, dr, R[2]);

        float fs = 0.0f;
        int ct = 0;
#pragma unroll
        for (int i = 0; i < RPS; ++i) { // full unroll: all ring indices compile-time
            if (i + 2 <= nr)            // prefetch row y0+i+2 (needed as B of step i+1)
                issue_row(base + (size_t)(y0 + i + 2) * W, dl, dr, R[(i + 3) & 3]);
            if (i < nr) {
                float Tw[18], Mw[18], Bw[18];
                unpack(R[i & 3],       Tw);
                unpack(R[(i + 1) & 3], Mw);
                unpack(R[(i + 2) & 3], Bw);
                do_row16(Tw, Mw, Bw, edge0, edge3, fs, ct);
            }
        }
        sum  += (double)fs;
        dcnt += (double)ct;             // wave-uniform
    }

    // per-lane fs -> wave sum; cnt already wave-uniform
    for (int off = 32; off > 0; off >>= 1)
        sum += __shfl_down(sum, off, 64);
    __shared__ double lsum[4], lcnt[4];
    if (lane == 0) { lsum[wv] = sum; lcnt[wv] = dcnt; }
    __syncthreads();
    if (q == 0) {
        partial[blockIdx.x]      = lsum[0] + lsum[1] + lsum[2] + lsum[3];
        partial[nb + blockIdx.x] = lcnt[0] + lcnt[1] + lcnt[2] + lcnt[3];
    }
}

__global__ __launch_bounds__(256) void curv_final(const double* __restrict__ partial,
                                                  int nb, float* __restrict__ out) {
    double s = 0.0, c = 0.0;
    for (int i = threadIdx.x; i < nb; i += 256) {
        s += partial[i];
        c += partial[nb + i];
    }
    for (int off = 32; off > 0; off >>= 1) {
        s += __shfl_down(s, off, 64);
        c += __shfl_down(c, off, 64);
    }
    __shared__ double lsum[4], lcnt[4];
    const int lane = threadIdx.x & 63, wv = threadIdx.x >> 6;
    if (lane == 0) { lsum[wv] = s; lcnt[wv] = c; }
    __syncthreads();
    if (threadIdx.x == 0) {
        const double S = lsum[0] + lsum[1] + lsum[2] + lsum[3];
        const double C = lcnt[0] + lcnt[1] + lcnt[2] + lcnt[3];
        out[0] = (float)(S / (C + 1e-8));
    }
}

extern "C" void kernel_launch(void* const* d_in, const int* in_sizes, int n_in,
                              void* d_out, int out_size, void* d_ws, size_t ws_size,
                              hipStream_t stream) {
    const float* phi = (const float*)d_in[0];
    float* out = (float*)d_out;
    double* partial = (double*)d_ws;

    int nb = NBLK;
    const size_t need = (size_t)nb * 2 * sizeof(double);
    if (ws_size < need) {
        nb = (int)(ws_size / (2 * sizeof(double)));
        if (nb < 1) nb = 1;
    }

    curv_partial<<<nb, 256, 0, stream>>>(phi, partial, nb);
    curv_final<<<1, 256, 0, stream>>>(partial, nb, out);
}

// Round 3
// 194.206 us; speedup vs baseline: 1.0337x; 1.0192x over previous
//
#include <hip/hip_runtime.h>
#include <math.h>
#include <float.h>

#define W 1024
#define IMG_SZ (1024*1024)
#define N_IMG 32
#define RPS 8                           // interior rows per strip
#define SPI 128                         // strips per image: 127*8 + 6 = 1022 interior rows
#define NSTRIP (N_IMG*SPI)              // 4096 strips, one per wave
#define NBLK 1024                       // 1024 blocks * 4 waves = 4096 waves (16 waves/CU)

// curv = Dxy*(Dx-Dy)^2 / (2h*(Dx^2+Dy^2)^1.5 + 16 h^4 * 1e-8)
#define TWO_H    0.122f
#define C_EPS    2.2153332e-12f        // 16 * 0.061^4 * 1e-8

// One image row, per-lane view: 16 contiguous px (x = 16*lane .. 16*lane+15).
// Halos come from neighbor lanes via ds_bpermute (no uncoalesced loads).
struct RowV { float4 a, b, c, d; };    // 16 VGPR
struct Halo { float l, r; };

__device__ __forceinline__ void issue_vec(const float* __restrict__ rp, RowV& v) {
    v.a = *reinterpret_cast<const float4*>(rp);
    v.b = *reinterpret_cast<const float4*>(rp + 4);
    v.c = *reinterpret_cast<const float4*>(rp + 8);
    v.d = *reinterpret_cast<const float4*>(rp + 12);
}

__device__ __forceinline__ float bperm(int addr, float x) {
    return __int_as_float(__builtin_amdgcn_ds_bpermute(addr, __float_as_int(x)));
}

// lane i: l = lane(i-1).d.w (px 15), r = lane(i+1).a.x (px 0); edges clamped
// (clamped values feed only edge-killed pixels)
__device__ __forceinline__ void make_halo(int addrL, int addrR, const RowV& v, Halo& h) {
    h.l = bperm(addrL, v.d.w);
    h.r = bperm(addrR, v.a.x);
}

__device__ __forceinline__ void unpack(const RowV& v, const Halo& h, float w[18]) {
    w[0]=h.l;
    w[1]=v.a.x;  w[2]=v.a.y;  w[3]=v.a.z;  w[4]=v.a.w;
    w[5]=v.b.x;  w[6]=v.b.y;  w[7]=v.b.z;  w[8]=v.b.w;
    w[9]=v.c.x;  w[10]=v.c.y; w[11]=v.c.z; w[12]=v.c.w;
    w[13]=v.d.x; w[14]=v.d.y; w[15]=v.d.z; w[16]=v.d.w;
    w[17]=h.r;
}

struct Px { float num, den, mn; };

__device__ __forceinline__ Px px(const float T[18], const float M[18], const float B[18], int j) {
    Px p;
    const float Dx  = M[j+2] - M[j];
    const float Dy  = B[j+1] - T[j+1];
    const float Dxy = (B[j+2] - B[j]) - T[j+2] + T[j];
    const float dif = Dx - Dy;
    p.num = Dxy * (dif * dif);
    const float s = Dx*Dx + Dy*Dy;
    p.den = TWO_H * (s * __builtin_amdgcn_sqrtf(s)) + C_EPS;
    const float c = M[j+1];
    p.mn = fminf(fminf(c*M[j], c*M[j+2]), fminf(c*T[j+1], c*B[j+1]));
    return p;
}

// shared reciprocal for two pixels: den>=C_EPS so den*den >= 4.9e-24 (no underflow)
__device__ __forceinline__ void pair(const Px& a, const Px& b, float ea, float eb,
                                     float& fsum, int& cnt) {
    const float rc = __builtin_amdgcn_rcpf(a.den * b.den);
    const float t0 = a.num * (b.den * rc);
    const float t1 = b.num * (a.den * rc);
    const float cr0 = fmaxf(t0*t0 - 1.0f, 0.0f);
    const float cr1 = fmaxf(t1*t1 - 1.0f, 0.0f);
    const bool k0 = fmaxf(a.mn, ea) < 0.0f;
    const bool k1 = fmaxf(b.mn, eb) < 0.0f;
    fsum += k0 ? cr0 : 0.0f;
    fsum += k1 ? cr1 : 0.0f;
    cnt += __popcll(__ballot(k0));     // scalar-pipe; cnt becomes wave-uniform
    cnt += __popcll(__ballot(k1));
}

__device__ __forceinline__ void do_row16(const float T[18], const float M[18], const float B[18],
                                         float e0, float e3, float& fsum, int& cnt) {
#pragma unroll
    for (int j = 0; j < 16; j += 2) {
        const Px p0 = px(T, M, B, j);
        const Px p1 = px(T, M, B, j + 1);
        pair(p0, p1, (j == 0) ? e0 : -FLT_MAX, (j == 14) ? e3 : -FLT_MAX, fsum, cnt);
    }
}

__global__ __launch_bounds__(256, 2) void curv_partial(const float* __restrict__ phi,
                                                       double* __restrict__ partial, int nb) {
    const int q = threadIdx.x;
    const int lane = q & 63;
    const int wv = q >> 6;
    const int addrL = ((lane == 0)  ? 0  : (lane - 1)) << 2;
    const int addrR = ((lane == 63) ? 63 : (lane + 1)) << 2;
    const float edge0 = (lane == 0)  ? 1.0f : -FLT_MAX;   // kills x=0
    const float edge3 = (lane == 63) ? 1.0f : -FLT_MAX;   // kills x=1023

    double sum = 0.0, dcnt = 0.0;
    const int nw = nb * 4;              // total waves

    // one strip (8 interior rows of one image) per wave; waves fully independent
    for (int sidx = (int)blockIdx.x * 4 + wv; sidx < NSTRIP; sidx += nw) {
        const int n = sidx >> 7;        // / SPI
        const int s = sidx & (SPI - 1);
        const int y0 = 1 + s * RPS;
        const int nr = (RPS < 1023 - y0) ? RPS : (1023 - y0);   // 8, last strip 6
        const float* base = phi + (size_t)n * IMG_SZ + lane * 16;

        RowV V[4];                      // ring: row (y0-1+t) in V[t&3]
        Halo H[4];
        issue_vec(base + (size_t)(y0 - 1) * W, V[0]);
        issue_vec(base + (size_t)(y0)     * W, V[1]);
        issue_vec(base + (size_t)(y0 + 1) * W, V[2]);
        make_halo(addrL, addrR, V[0], H[0]);   // waits V0 loads (vmcnt(8))
        make_halo(addrL, addrR, V[1], H[1]);   // waits V1 loads (vmcnt(4))

        float fs = 0.0f;
        int ct = 0;
        // unroll by ring period 4 -> all ring indices compile-time, body ~15 KB
        for (int i4 = 0; i4 < RPS; i4 += 4) {
#pragma unroll
            for (int k = 0; k < 4; ++k) {
                const int i = i4 + k;
                if (i < nr) {
                    // prefetch row y0+i+2 (B of step i+1); clamp harmless (unused or valid)
                    int pr = y0 + i + 2;
                    if (pr > 1023) pr = 1023;
                    issue_vec(base + (size_t)pr * W, V[(k + 3) & 3]);
                    // finish halo of this step's B row (loaded last step; vmcnt(4) wait)
                    make_halo(addrL, addrR, V[(k + 2) & 3], H[(k + 2) & 3]);
                    float Tw[18], Mw[18], Bw[18];
                    unpack(V[k & 3],       H[k & 3],       Tw);
                    unpack(V[(k + 1) & 3], H[(k + 1) & 3], Mw);
                    unpack(V[(k + 2) & 3], H[(k + 2) & 3], Bw);
                    do_row16(Tw, Mw, Bw, edge0, edge3, fs, ct);
                }
            }
        }
        sum  += (double)fs;
        dcnt += (double)ct;             // wave-uniform
    }

    // per-lane fs -> wave sum; cnt already wave-uniform
    for (int off = 32; off > 0; off >>= 1)
        sum += __shfl_down(sum, off, 64);
    __shared__ double lsum[4], lcnt[4];
    if (lane == 0) { lsum[wv] = sum; lcnt[wv] = dcnt; }
    __syncthreads();
    if (q == 0) {
        partial[blockIdx.x]      = lsum[0] + lsum[1] + lsum[2] + lsum[3];
        partial[nb + blockIdx.x] = lcnt[0] + lcnt[1] + lcnt[2] + lcnt[3];
    }
}

__global__ __launch_bounds__(256) void curv_final(const double* __restrict__ partial,
                                                  int nb, float* __restrict__ out) {
    double s = 0.0, c = 0.0;
    for (int i = threadIdx.x; i < nb; i += 256) {
        s += partial[i];
        c += partial[nb + i];
    }
    for (int off = 32; off > 0; off >>= 1) {
        s += __shfl_down(s, off, 64);
        c += __shfl_down(c, off, 64);
    }
    __shared__ double lsum[4], lcnt[4];
    const int lane = threadIdx.x & 63, wv = threadIdx.x >> 6;
    if (lane == 0) { lsum[wv] = s; lcnt[wv] = c; }
    __syncthreads();
    if (threadIdx.x == 0) {
        const double S = lsum[0] + lsum[1] + lsum[2] + lsum[3];
        const double C = lcnt[0] + lcnt[1] + lcnt[2] + lcnt[3];
        out[0] = (float)(S / (C + 1e-8));
    }
}

extern "C" void kernel_launch(void* const* d_in, const int* in_sizes, int n_in,
                              void* d_out, int out_size, void* d_ws, size_t ws_size,
                              hipStream_t stream) {
    const float* phi = (const float*)d_in[0];
    float* out = (float*)d_out;
    double* partial = (double*)d_ws;

    int nb = NBLK;
    const size_t need = (size_t)nb * 2 * sizeof(double);
    if (ws_size < need) {
        nb = (int)(ws_size / (2 * sizeof(double)));
        if (nb < 1) nb = 1;
    }

    curv_partial<<<nb, 256, 0, stream>>>(phi, partial, nb);
    curv_final<<<1, 256, 0, stream>>>(partial, nb, out);
}